// Round 5
// baseline (200.356 us; speedup 1.0000x reference)
//
#include <hip/hip_runtime.h>

#define B_SZ    64
#define S_LEN   448
#define D_MODEL 1024
#define N_HEAD  16
#define D_HEAD  64
#define CHUNK   28
#define NCH     16    // 16 * 28 = 448
#define PF      8     // prefetch depth (rows)
#define CPY_BLK 2048

typedef float f4 __attribute__((ext_vector_type(4)));

// ---------------------------------------------------------------------------
// GEMM partial: P[(mat*8+kt)][b][n] = sum_{k in kt-range} X[b][k] * W[k][n]
// grid = (16 ntiles, 8 ktiles, nmat), block = 256
// ---------------------------------------------------------------------------
__global__ __launch_bounds__(256) void gemm_part(
    const float* __restrict__ X,
    const float* __restrict__ W0, const float* __restrict__ W1,
    const float* __restrict__ W2,
    float* __restrict__ P)
{
    const int nt  = blockIdx.x;
    const int kt  = blockIdx.y;
    const int mat = blockIdx.z;
    const float* __restrict__ W = (mat == 0) ? W0 : ((mat == 1) ? W1 : W2);

    const int t  = threadIdx.x;
    const int n  = nt * 64 + (t & 63);
    const int b0 = __builtin_amdgcn_readfirstlane((t >> 6) * 16);
    const int k0 = kt * 128;

    float acc[16];
#pragma unroll
    for (int j = 0; j < 16; ++j) acc[j] = 0.f;

#pragma unroll 8
    for (int k = k0; k < k0 + 128; ++k) {
        const float w = W[k * D_MODEL + n];
#pragma unroll
        for (int j = 0; j < 16; ++j)
            acc[j] += X[(b0 + j) * D_MODEL + k] * w;
    }

    float* p = P + (size_t)(mat * 8 + kt) * (B_SZ * D_MODEL);
#pragma unroll
    for (int j = 0; j < 16; ++j)
        p[(b0 + j) * D_MODEL + n] = acc[j];
}

// reduce 8 k-partials + bias -> final out projection
__global__ __launch_bounds__(256) void reduce_out(
    const float* __restrict__ P, const float* __restrict__ bo,
    float* __restrict__ out)
{
    const int i = blockIdx.x * 256 + threadIdx.x;     // < 65536
    float s = bo[i & (D_MODEL - 1)];
#pragma unroll
    for (int kt = 0; kt < 8; ++kt)
        s += P[(size_t)kt * 65536 + i];
    out[i] = s;
}

// ---------------------------------------------------------------------------
// Attention partials, READ-ONLY (no cache-copy stores), online softmax,
// 8-row register prefetch. grid = (NCH, B), block = 256.
// ---------------------------------------------------------------------------
__global__ __launch_bounds__(256) void attn_read(
    const float* __restrict__ kcache, const float* __restrict__ vcache,
    const float* __restrict__ part,   // [24][64][1024]: q 0-7, k 8-15, v 16-23
    const float* __restrict__ bq, const float* __restrict__ bv,
    const float* __restrict__ amask, const int* __restrict__ idxp,
    float* __restrict__ accws, float* __restrict__ mlws)
{
    const int c   = blockIdx.x;
    const int b   = blockIdx.y;
    const int t   = threadIdx.x;
    const int col = t * 4;
    const int h   = t >> 4;
    const int l16 = t & 15;
    const int idx = idxp[0];
    const int s0  = c * CHUNK;

    // q = sum of 8 k-split partials + bias (scale 0.125 applied to score)
    f4 q = *(const f4*)(bq + col);
#pragma unroll
    for (int kt = 0; kt < 8; ++kt)
        q += *(const f4*)(part + (size_t)kt * 65536 + b * D_MODEL + col);

    // new-token k/v rows, only for the chunk that owns idx
    f4 knew = (f4)0.f, vnew = (f4)0.f;
    if ((idx >= s0) && (idx < s0 + CHUNK)) {
#pragma unroll
        for (int kt = 0; kt < 8; ++kt) {
            knew += *(const f4*)(part + (size_t)(8 + kt)  * 65536 + b * D_MODEL + col);
            vnew += *(const f4*)(part + (size_t)(16 + kt) * 65536 + b * D_MODEL + col);
        }
        vnew += *(const f4*)(bv + col);
    }

    const size_t base = (size_t)(b * S_LEN + s0) * D_MODEL + col;

    f4 kb[PF], vb[PF];
#pragma unroll
    for (int r = 0; r < PF; ++r) {
        kb[r] = *(const f4*)(kcache + base + (size_t)r * D_MODEL);
        vb[r] = *(const f4*)(vcache + base + (size_t)r * D_MODEL);
    }

    float m = -1e30f, l = 0.f;
    f4 acc = (f4)0.f;

#pragma unroll
    for (int s = 0; s < CHUNK; ++s) {
        f4 k4 = kb[s & (PF - 1)];
        f4 v4 = vb[s & (PF - 1)];
        if (s + PF < CHUNK) {
            kb[s & (PF - 1)] = *(const f4*)(kcache + base + (size_t)(s + PF) * D_MODEL);
            vb[s & (PF - 1)] = *(const f4*)(vcache + base + (size_t)(s + PF) * D_MODEL);
        }
        const int srow = s0 + s;
        if (srow == idx) { k4 = knew; v4 = vnew; }

        float p = q.x * k4.x + q.y * k4.y + q.z * k4.z + q.w * k4.w;
        p += __shfl_xor(p, 1);
        p += __shfl_xor(p, 2);
        p += __shfl_xor(p, 4);
        p += __shfl_xor(p, 8);
        p = p * 0.125f + amask[srow];

        const float mn = fmaxf(m, p);
        const float f  = __expf(m - mn);
        const float w  = __expf(p - mn);
        l = l * f + w;
        acc.x = acc.x * f + w * v4.x;
        acc.y = acc.y * f + w * v4.y;
        acc.z = acc.z * f + w * v4.z;
        acc.w = acc.w * f + w * v4.w;
        m = mn;
    }

    float* ap = accws + ((size_t)(b * N_HEAD + h) * NCH + c) * D_HEAD + l16 * 4;
    *(f4*)ap = acc;
    if (l16 == 0) {
        const int w = (b * N_HEAD + h) * NCH + c;
        mlws[w * 2]     = m;
        mlws[w * 2 + 1] = l;
    }
}

// ---------------------------------------------------------------------------
// Pure streaming copy of both caches (stale idx row included; fixed up after).
// grid-stride, branch-free: memcpy-shaped so stores depend only on own loads.
// ---------------------------------------------------------------------------
__global__ __launch_bounds__(256) void cache_copy(
    const float* __restrict__ kcache, const float* __restrict__ vcache,
    float* __restrict__ kout, float* __restrict__ vout)
{
    const size_t n4     = (size_t)B_SZ * S_LEN * D_MODEL / 4;  // 7,340,032
    const size_t stride = (size_t)CPY_BLK * 256;               // 524,288
    const f4* __restrict__ ks = (const f4*)kcache;
    const f4* __restrict__ vs = (const f4*)vcache;
    f4* __restrict__ kd = (f4*)kout;
    f4* __restrict__ vd = (f4*)vout;
    size_t i = (size_t)blockIdx.x * 256 + threadIdx.x;
#pragma unroll 7
    for (; i < n4; i += stride) {
        __builtin_nontemporal_store(ks[i], kd + i);
        __builtin_nontemporal_store(vs[i], vd + i);
    }
}

// overwrite row idx of kout/vout with the new token's k/v (from partials 8-23)
__global__ __launch_bounds__(256) void kv_fix(
    const float* __restrict__ part, const float* __restrict__ bv,
    const int* __restrict__ idxp,
    float* __restrict__ kout, float* __restrict__ vout)
{
    const int b   = blockIdx.x;
    const int col = threadIdx.x * 4;
    const int idx = idxp[0];
    f4 kn = (f4)0.f, vn = (f4)0.f;
#pragma unroll
    for (int kt = 0; kt < 8; ++kt) {
        kn += *(const f4*)(part + (size_t)(8 + kt)  * 65536 + b * D_MODEL + col);
        vn += *(const f4*)(part + (size_t)(16 + kt) * 65536 + b * D_MODEL + col);
    }
    vn += *(const f4*)(bv + col);
    const size_t roff = (size_t)(b * S_LEN + idx) * D_MODEL + col;
    *(f4*)(kout + roff) = kn;
    *(f4*)(vout + roff) = vn;
}

// combine chunk partials -> wv[b][h*64+d]
__global__ __launch_bounds__(256) void combine(
    const float* __restrict__ accws, const float* __restrict__ mlws,
    float* __restrict__ wvws)
{
    const int t = threadIdx.x;
    const int w = blockIdx.x * 4 + (t >> 6);   // (b*16+h), 0..1023
    const int d = t & 63;

    float M = -1e30f;
#pragma unroll
    for (int c = 0; c < NCH; ++c)
        M = fmaxf(M, mlws[(w * NCH + c) * 2]);
    float L = 0.f, O = 0.f;
#pragma unroll
    for (int c = 0; c < NCH; ++c) {
        const float f = __expf(mlws[(w * NCH + c) * 2] - M);
        L += mlws[(w * NCH + c) * 2 + 1] * f;
        O += accws[(w * NCH + c) * D_HEAD + d] * f;
    }
    const int b = w >> 4, h = w & 15;
    wvws[b * D_MODEL + h * D_HEAD + d] = O / L;
}

// ---------------------------------------------------------------------------
extern "C" void kernel_launch(void* const* d_in, const int* in_sizes, int n_in,
                              void* d_out, int out_size, void* d_ws, size_t ws_size,
                              hipStream_t stream) {
    const float* x      = (const float*)d_in[0];
    const float* kcache = (const float*)d_in[1];
    const float* vcache = (const float*)d_in[2];
    const int*   idxp   = (const int*)d_in[3];
    const float* amask  = (const float*)d_in[4];
    const float* Wq     = (const float*)d_in[5];
    const float* bq     = (const float*)d_in[6];
    const float* Wk     = (const float*)d_in[7];
    const float* Wv     = (const float*)d_in[8];
    const float* bv     = (const float*)d_in[9];
    const float* Wo     = (const float*)d_in[10];
    const float* bo     = (const float*)d_in[11];

    float* out  = (float*)d_out;                 // [64][1024]
    float* kout = out + 65536;                   // [64][448][1024]
    float* vout = kout + (size_t)B_SZ * S_LEN * D_MODEL;

    float* ws    = (float*)d_ws;
    float* part  = ws;                 // 24*65536 = 1572864
    float* accws = ws + 1572864;       // 1024*16*64 = 1048576
    float* mlws  = ws + 2621440;       // 32768
    float* wvws  = ws + 2654208;       // 65536   (total ~10.9 MB)

    // q/k/v projections (k-split partials; biases folded downstream)
    gemm_part<<<dim3(16, 8, 3), 256, 0, stream>>>(x, Wq, Wk, Wv, part);

    // attention partials — read-only pass over the caches
    attn_read<<<dim3(NCH, B_SZ), 256, 0, stream>>>(
        kcache, vcache, part, bq, bv, amask, idxp, accws, mlws);

    // softmax combine -> wv
    combine<<<256, 256, 0, stream>>>(accws, mlws, wvws);

    // output projection: mat=0 -> writes part slots 0-7 ONLY (q partials,
    // dead after attn_read). Slots 8-23 (k/v partials) stay intact for kv_fix.
    gemm_part<<<dim3(16, 8, 1), 256, 0, stream>>>(wvws, Wo, Wo, Wo, part);
    reduce_out<<<256, 256, 0, stream>>>(part, bo, out);

    // cache clone (pure memcpy) + idx-row fixup from k/v partials
    cache_copy<<<CPY_BLK, 256, 0, stream>>>(kcache, vcache, kout, vout);
    kv_fix<<<B_SZ, 256, 0, stream>>>(part, bv, idxp, kout, vout);
}

// Round 6
// 167.347 us; speedup vs baseline: 1.1973x; 1.1973x over previous
//
#include <hip/hip_runtime.h>

#define B_SZ    64
#define S_LEN   448
#define D_MODEL 1024
#define N_HEAD  16
#define D_HEAD  64
#define CHUNK   28
#define NCH     16    // 16 * 28 = 448

typedef float f4 __attribute__((ext_vector_type(4)));

// ---------------------------------------------------------------------------
// GEMM partial: P[(mat*8+kt)][b][n] = sum_{k in kt-range} X[b][k] * W[k][n]
// grid = (16 ntiles, 8 ktiles, nmat), block = 256
// ---------------------------------------------------------------------------
__global__ __launch_bounds__(256) void gemm_part(
    const float* __restrict__ X,
    const float* __restrict__ W0, const float* __restrict__ W1,
    const float* __restrict__ W2,
    float* __restrict__ P)
{
    const int nt  = blockIdx.x;
    const int kt  = blockIdx.y;
    const int mat = blockIdx.z;
    const float* __restrict__ W = (mat == 0) ? W0 : ((mat == 1) ? W1 : W2);

    const int t  = threadIdx.x;
    const int n  = nt * 64 + (t & 63);
    const int b0 = __builtin_amdgcn_readfirstlane((t >> 6) * 16);
    const int k0 = kt * 128;

    float acc[16];
#pragma unroll
    for (int j = 0; j < 16; ++j) acc[j] = 0.f;

#pragma unroll 8
    for (int k = k0; k < k0 + 128; ++k) {
        const float w = W[k * D_MODEL + n];
#pragma unroll
        for (int j = 0; j < 16; ++j)
            acc[j] += X[(b0 + j) * D_MODEL + k] * w;
    }

    float* p = P + (size_t)(mat * 8 + kt) * (B_SZ * D_MODEL);
#pragma unroll
    for (int j = 0; j < 16; ++j)
        p[(b0 + j) * D_MODEL + n] = acc[j];
}

// reduce 8 k-partials + bias -> final out projection
__global__ __launch_bounds__(256) void reduce_out(
    const float* __restrict__ P, const float* __restrict__ bo,
    float* __restrict__ out)
{
    const int i = blockIdx.x * 256 + threadIdx.x;     // < 65536
    float s = bo[i & (D_MODEL - 1)];
#pragma unroll
    for (int kt = 0; kt < 8; ++kt)
        s += P[(size_t)kt * 65536 + i];
    out[i] = s;
}

// ---------------------------------------------------------------------------
// Fused cache-copy + attention partials, THREE-PHASE, chain-free streams.
// grid = (NCH, B), block = 256. Thread t: cols 4t..4t+3, head h = t>>4.
// Phase 1: K stream (load/idx-fix/nt-store/dot -> p[s], independent iters).
// Phase 2: off-stream softmax: 28 independent shuffle butterflies, then
//          scale+mask+max+exp entirely in registers (all lanes redundant).
// Phase 3: V stream (load/idx-fix/nt-store/fma, only a 4-cyc acc chain).
// ---------------------------------------------------------------------------
__global__ __launch_bounds__(256) void stream_attn(
    const float* __restrict__ kcache, const float* __restrict__ vcache,
    const float* __restrict__ part,   // [24][64][1024]: q 0-7, k 8-15, v 16-23
    const float* __restrict__ bq, const float* __restrict__ bv,
    const float* __restrict__ amask, const int* __restrict__ idxp,
    float* __restrict__ kout, float* __restrict__ vout,
    float* __restrict__ accws, float* __restrict__ mlws)
{
    const int c   = blockIdx.x;
    const int b   = blockIdx.y;
    const int t   = threadIdx.x;
    const int col = t * 4;
    const int h   = t >> 4;
    const int l16 = t & 15;
    const int idx = idxp[0];
    const int s0  = c * CHUNK;

    // q = sum of 8 k-split partials + bias (scale 0.125 applied to score)
    f4 q = *(const f4*)(bq + col);
#pragma unroll
    for (int kt = 0; kt < 8; ++kt)
        q += *(const f4*)(part + (size_t)kt * 65536 + b * D_MODEL + col);

    // new-token k/v rows, only for the chunk that owns idx
    f4 knew = (f4)0.f, vnew = (f4)0.f;
    if ((idx >= s0) && (idx < s0 + CHUNK)) {
#pragma unroll
        for (int kt = 0; kt < 8; ++kt) {
            knew += *(const f4*)(part + (size_t)(8 + kt)  * 65536 + b * D_MODEL + col);
            vnew += *(const f4*)(part + (size_t)(16 + kt) * 65536 + b * D_MODEL + col);
        }
        vnew += *(const f4*)(bv + col);
    }

    const size_t base = (size_t)(b * S_LEN + s0) * D_MODEL + col;

    // ---- Phase 1: K stream + per-thread dot partials (independent iters)
    float p[CHUNK];
#pragma unroll
    for (int s = 0; s < CHUNK; ++s) {
        f4 k4 = *(const f4*)(kcache + base + (size_t)s * D_MODEL);
        if (s0 + s == idx) k4 = knew;
        __builtin_nontemporal_store(k4, (f4*)(kout + base + (size_t)s * D_MODEL));
        p[s] = q.x * k4.x + q.y * k4.y + q.z * k4.z + q.w * k4.w;
    }

    // ---- Phase 2: 28 independent 16-lane butterflies (pipeline freely),
    //      then softmax in registers (redundant across the head's 16 lanes)
#pragma unroll
    for (int s = 0; s < CHUNK; ++s) {
        float v = p[s];
        v += __shfl_xor(v, 1);
        v += __shfl_xor(v, 2);
        v += __shfl_xor(v, 4);
        v += __shfl_xor(v, 8);
        p[s] = v * 0.125f + amask[s0 + s];
    }
    float m = p[0];
#pragma unroll
    for (int s = 1; s < CHUNK; ++s) m = fmaxf(m, p[s]);
    float l = 0.f;
#pragma unroll
    for (int s = 0; s < CHUNK; ++s) { p[s] = __expf(p[s] - m); l += p[s]; }

    // ---- Phase 3: V stream + weighted accumulate (only 4-cyc FMA chain)
    f4 acc = (f4)0.f;
#pragma unroll
    for (int s = 0; s < CHUNK; ++s) {
        f4 v4 = *(const f4*)(vcache + base + (size_t)s * D_MODEL);
        if (s0 + s == idx) v4 = vnew;
        __builtin_nontemporal_store(v4, (f4*)(vout + base + (size_t)s * D_MODEL));
        acc.x += p[s] * v4.x;
        acc.y += p[s] * v4.y;
        acc.z += p[s] * v4.z;
        acc.w += p[s] * v4.w;
    }

    // store partials: acc[(b*16+h)][c][64], ml[(b*16+h)][c][2]
    float* ap = accws + ((size_t)(b * N_HEAD + h) * NCH + c) * D_HEAD + l16 * 4;
    *(f4*)ap = acc;
    if (l16 == 0) {
        const int w = (b * N_HEAD + h) * NCH + c;
        mlws[w * 2]     = m;
        mlws[w * 2 + 1] = l;
    }
}

// combine chunk partials -> wv[b][h*64+d]
__global__ __launch_bounds__(256) void combine(
    const float* __restrict__ accws, const float* __restrict__ mlws,
    float* __restrict__ wvws)
{
    const int t = threadIdx.x;
    const int w = blockIdx.x * 4 + (t >> 6);   // (b*16+h), 0..1023
    const int d = t & 63;

    float M = -1e30f;
#pragma unroll
    for (int c = 0; c < NCH; ++c)
        M = fmaxf(M, mlws[(w * NCH + c) * 2]);
    float L = 0.f, O = 0.f;
#pragma unroll
    for (int c = 0; c < NCH; ++c) {
        const float f = __expf(mlws[(w * NCH + c) * 2] - M);
        L += mlws[(w * NCH + c) * 2 + 1] * f;
        O += accws[(w * NCH + c) * D_HEAD + d] * f;
    }
    const int b = w >> 4, h = w & 15;
    wvws[b * D_MODEL + h * D_HEAD + d] = O / L;
}

// ---------------------------------------------------------------------------
extern "C" void kernel_launch(void* const* d_in, const int* in_sizes, int n_in,
                              void* d_out, int out_size, void* d_ws, size_t ws_size,
                              hipStream_t stream) {
    const float* x      = (const float*)d_in[0];
    const float* kcache = (const float*)d_in[1];
    const float* vcache = (const float*)d_in[2];
    const int*   idxp   = (const int*)d_in[3];
    const float* amask  = (const float*)d_in[4];
    const float* Wq     = (const float*)d_in[5];
    const float* bq     = (const float*)d_in[6];
    const float* Wk     = (const float*)d_in[7];
    const float* Wv     = (const float*)d_in[8];
    const float* bv     = (const float*)d_in[9];
    const float* Wo     = (const float*)d_in[10];
    const float* bo     = (const float*)d_in[11];

    float* out  = (float*)d_out;                 // [64][1024]
    float* kout = out + 65536;                   // [64][448][1024]
    float* vout = kout + (size_t)B_SZ * S_LEN * D_MODEL;

    float* ws    = (float*)d_ws;
    float* part  = ws;                 // 24*65536 = 1572864
    float* accws = ws + 1572864;       // 1024*16*64 = 1048576
    float* mlws  = ws + 2621440;       // 32768
    float* wvws  = ws + 2654208;       // 65536   (total ~10.9 MB)

    // q/k/v projections (k-split partials; biases folded downstream)
    gemm_part<<<dim3(16, 8, 3), 256, 0, stream>>>(x, Wq, Wk, Wv, part);

    // fused cache update + attention partials (three-phase, chain-free)
    stream_attn<<<dim3(NCH, B_SZ), 256, 0, stream>>>(
        kcache, vcache, part, bq, bv, amask, idxp,
        kout, vout, accws, mlws);

    // softmax combine -> wv
    combine<<<256, 256, 0, stream>>>(accws, mlws, wvws);

    // output projection: mat=0 writes part slots 0-7 only (q partials, dead
    // after stream_attn); k/v slots 8-23 are no longer needed afterwards.
    gemm_part<<<dim3(16, 8, 1), 256, 0, stream>>>(wvws, Wo, Wo, Wo, part);
    reduce_out<<<256, 256, 0, stream>>>(part, bo, out);
}